// Round 5
// baseline (4627.351 us; speedup 1.0000x reference)
//
#include <hip/hip_runtime.h>
#include <hip/hip_bf16.h>
#include <math.h>

#define B_ 32
#define T_ 512
#define D_ 1024
#define H_ 1024
#define G4 4096
#define BT 16384
#define NWG 64

using bf16x8 = __attribute__((ext_vector_type(8))) short;
using f32x4  = __attribute__((ext_vector_type(4))) float;
typedef unsigned long long u64;

__device__ __forceinline__ float sigm(float x) { return 1.0f / (1.0f + __expf(-x)); }

// ---- workspace layout (bytes) ----
#define OFF_FLG   0ull                         // 64 flags, 64B stride = 4096 B
#define OFF_HBUF  4096ull                      // (unused now, kept for layout stability)
#define OFF_WHB   (OFF_HBUF + 131072ull)       // Wh bf16 [4096][1024] = 8388608
#define OFF_WXB   (OFF_WHB + 8388608ull)       // Wx bf16 = 8388608
#define OFF_INPB  (OFF_WXB + 8388608ull)       // inp bf16 (then reused as hseq[T][B][H]) = 33554432
#define OFF_BXH   (OFF_INPB + 33554432ull)     // bx+bh f32 [4096] = 16384
#define OFF_XG    (OFF_BXH + 16384ull)         // xg bf16 [T][4][NWG][32][16] = 134217728
#define WS_NEEDED (OFF_XG + 134217728ull)

// LDS layout for lstm_scan (dynamic):
//   [0, 65536)          h-stage: 32 rows x 2048 B, XOR-swizzled
//   [65536, 74240)      gbuf: [32][4][17] f32 = 8704 B
//   [74240, 75264)      hpack: [32][16] ushort = 1024 B
#define SMEM_STAGE  0
#define SMEM_GBUF   65536
#define SMEM_HPACK  74240
#define SMEM_TOTAL  75264

// ============ phase 1: convert inputs to bf16, fold biases ============
__global__ __launch_bounds__(256) void convert_all(
    const float* __restrict__ inp, const float* __restrict__ Wx,
    const float* __restrict__ bx, const float* __restrict__ Wh,
    const float* __restrict__ bh,
    __hip_bfloat16* __restrict__ inp_b, __hip_bfloat16* __restrict__ Wx_b,
    __hip_bfloat16* __restrict__ Wh_b, float* __restrict__ bxh)
{
    const int gid = blockIdx.x * 256 + threadIdx.x;   // 0 .. 1048575
    {
        const float4* s = (const float4*)inp + (size_t)gid * 4;
        #pragma unroll
        for (int v = 0; v < 4; ++v) {
            float4 f = s[v];
            size_t base = (size_t)gid * 16 + v * 4;
            inp_b[base + 0] = __float2bfloat16(f.x);
            inp_b[base + 1] = __float2bfloat16(f.y);
            inp_b[base + 2] = __float2bfloat16(f.z);
            inp_b[base + 3] = __float2bfloat16(f.w);
        }
    }
    {
        float4 fx = ((const float4*)Wx)[gid];
        float4 fh = ((const float4*)Wh)[gid];
        size_t base = (size_t)gid * 4;
        Wx_b[base + 0] = __float2bfloat16(fx.x);
        Wx_b[base + 1] = __float2bfloat16(fx.y);
        Wx_b[base + 2] = __float2bfloat16(fx.z);
        Wx_b[base + 3] = __float2bfloat16(fx.w);
        Wh_b[base + 0] = __float2bfloat16(fh.x);
        Wh_b[base + 1] = __float2bfloat16(fh.y);
        Wh_b[base + 2] = __float2bfloat16(fh.z);
        Wh_b[base + 3] = __float2bfloat16(fh.w);
    }
    if (gid < G4) bxh[gid] = bx[gid] + bh[gid];
}

// ============ phase 2: xg = X @ Wx^T + (bx+bh), store [T][4][NWG][32][16] ============
__global__ __launch_bounds__(256) void xg_gemm(
    const __hip_bfloat16* __restrict__ X,    // [BT][D], row = b*T + t
    const __hip_bfloat16* __restrict__ Wxb,  // [G4][D]
    const float* __restrict__ bxh,           // [G4]
    __hip_bfloat16* __restrict__ xg)         // [T][4][NWG][32][16]
{
    const int m0 = blockIdx.x * 128;
    const int n0 = blockIdx.y * 64;
    const int lane = threadIdx.x & 63;
    const int wave = threadIdx.x >> 6;
    const int l15 = lane & 15;
    const int kg = (lane >> 4) * 8;

    f32x4 acc[2][4] = {};
    const __hip_bfloat16* xrow0 = X + (size_t)(m0 + wave * 16 + l15) * D_;
    const __hip_bfloat16* xrow1 = xrow0 + (size_t)64 * D_;
    for (int k0 = 0; k0 < D_; k0 += 32) {
        bf16x8 a0 = *(const bf16x8*)(xrow0 + k0 + kg);
        bf16x8 a1 = *(const bf16x8*)(xrow1 + k0 + kg);
        #pragma unroll
        for (int n = 0; n < 4; ++n) {
            bf16x8 b = *(const bf16x8*)(Wxb + (size_t)(n0 + n * 16 + l15) * D_ + k0 + kg);
            acc[0][n] = __builtin_amdgcn_mfma_f32_16x16x32_bf16(a0, b, acc[0][n], 0, 0, 0);
            acc[1][n] = __builtin_amdgcn_mfma_f32_16x16x32_bf16(a1, b, acc[1][n], 0, 0, 0);
        }
    }
    #pragma unroll
    for (int g = 0; g < 2; ++g) {
        const int r0 = m0 + g * 64 + wave * 16 + ((lane >> 4) << 2);
        #pragma unroll
        for (int n = 0; n < 4; ++n) {
            const int col = n0 + n * 16 + l15;
            const int qq  = col >> 10;
            const int ww  = (col >> 4) & 63;
            const int jj  = col & 15;
            const float bias = bxh[col];
            #pragma unroll
            for (int r = 0; r < 4; ++r) {
                const int row = r0 + r;                 // = b*T + t
                const int bb = row >> 9, tt = row & 511;
                xg[((((size_t)tt * 4 + qq) * NWG + ww) * 32 + bb) * 16 + jj] =
                    __float2bfloat16(acc[g][n][r] + bias);
            }
        }
    }
}

// ============ phase 3: persistent recurrent scan (fence-free, minimal stores) ============
// 64 WGs x 512 threads, 1 WG/CU (no launch cap -> 256 VGPR budget, bfrag stays resident).
// h history in hseq[T][B][H] bf16 (agent-coherent UC traffic only; no cache maintenance).
// Per step: wave0 polls flags -> all stage h into LDS -> 32 MFMA -> gates -> hpack(LDS)
// -> wave0 stores 1KB packed h + publishes flag after in-wave vmcnt(0). No f32 out here.
__global__ __launch_bounds__(512) void lstm_scan(
    const __hip_bfloat16* __restrict__ xg,    // [T][4][NWG][32][16] (bias folded)
    const __hip_bfloat16* __restrict__ Whb,   // [G4][H]
    __hip_bfloat16* __restrict__ hseq,        // [T][B][H]
    unsigned int* __restrict__ flags)         // [NWG] at 16-uint (64B) stride
{
    extern __shared__ char smem[];
    float* gbuf = (float*)(smem + SMEM_GBUF);
    unsigned short* hpack = (unsigned short*)(smem + SMEM_HPACK);

    const int w    = blockIdx.x;
    const int tid  = threadIdx.x;
    const int lane = tid & 63;
    const int wave = tid >> 6;
    const int mwave = wave >> 2;       // 0..1
    const int q     = wave & 3;        // gate
    const int l15   = lane & 15;
    const int kg    = (lane >> 4) * 8;

    // ---- pin this wave's Wh B-fragments in registers (UC loads, 128 VGPR) ----
    bf16x8 bfrag[32];
    {
        const char* wrow = (const char*)(Whb + (size_t)(q * 1024 + w * 16 + l15) * H_);
        #pragma unroll
        for (int i = 0; i < 32; ++i) {
            u64 lo = __hip_atomic_load((const u64*)(wrow + (i * 32 + kg) * 2),
                                       __ATOMIC_RELAXED, __HIP_MEMORY_SCOPE_AGENT);
            u64 hi = __hip_atomic_load((const u64*)(wrow + (i * 32 + kg) * 2 + 8),
                                       __ATOMIC_RELAXED, __HIP_MEMORY_SCOPE_AGENT);
            union { u64 qv[2]; bf16x8 v; } u;
            u.qv[0] = lo; u.qv[1] = hi;
            bfrag[i] = u.v;
        }
    }

    // pointwise ownership: thread = (batch, jj)
    const int pb  = tid >> 4;          // 0..31
    const int pjj = tid & 15;
    float cst = 0.0f;

    const int dbr  = mwave * 16 + ((lane >> 4) << 2);   // batch-row base of D-tile
    const int arow = mwave * 16 + l15;                  // A-frag batch row
    const int abase = arow * 2048;
    const int axor  = (arow & 7) << 4;
    const int srow = wave * 4 + (lane >> 4);            // staging row 0..31
    const int ql   = lane & 15;

    for (int t = 0; t < T_; ++t) {
        // xg prefetch (cached loads, contiguous per-WG slab) — independent of h
        float xgv[4];
        {
            const size_t sbase = (((size_t)t * 4 + q) * NWG + w) * 512;
            #pragma unroll
            for (int r = 0; r < 4; ++r)
                xgv[r] = __bfloat162float(xg[sbase + (dbr + r) * 16 + l15]);
        }

        f32x4 acc0 = {}, acc1 = {};
        if (t > 0) {
            // ---- wait for all WGs to publish h_{t-1} ----
            if (wave == 0) {
                const unsigned int* fp = flags + lane * 16;
                while (__hip_atomic_load(fp, __ATOMIC_RELAXED, __HIP_MEMORY_SCOPE_AGENT)
                       < (unsigned)t)
                    __builtin_amdgcn_s_sleep(1);
            }
            __syncthreads();   // (1) poll-sync

            // ---- stage h_{t-1} into LDS (UC u64 loads, XOR-swizzled writes) ----
            {
                const u64* src = (const u64*)(hseq + ((size_t)(t - 1) * B_ + srow) * H_);
                #pragma unroll
                for (int j = 0; j < 16; ++j) {
                    u64 v = __hip_atomic_load(src + ql + j * 16,
                                              __ATOMIC_RELAXED, __HIP_MEMORY_SCOPE_AGENT);
                    *(u64*)(smem + srow * 2048 + (((ql + j * 16) * 8) ^ ((srow & 7) << 4))) = v;
                }
            }
            __syncthreads();   // (2) stage-sync

            // ---- 32 MFMAs: acc = h_{t-1} @ Wh^T (two chains) ----
            #pragma unroll
            for (int i = 0; i < 16; ++i) {
                bf16x8 a0 = *(const bf16x8*)(smem + abase + (((i * 64 + kg) * 2) ^ axor));
                bf16x8 a1 = *(const bf16x8*)(smem + abase + (((i * 64 + 32 + kg) * 2) ^ axor));
                acc0 = __builtin_amdgcn_mfma_f32_16x16x32_bf16(a0, bfrag[2 * i + 0], acc0, 0, 0, 0);
                acc1 = __builtin_amdgcn_mfma_f32_16x16x32_bf16(a1, bfrag[2 * i + 1], acc1, 0, 0, 0);
            }
        }

        #pragma unroll
        for (int r = 0; r < 4; ++r)
            gbuf[((dbr + r) * 4 + q) * 17 + l15] = acc0[r] + acc1[r] + xgv[r];
        __syncthreads();   // (3) gbuf-sync (gbuf separate from stage -> no alias hazard)

        // ---- pointwise gate update; c stays in a register; h -> LDS hpack ----
        {
            float gi = sigm(gbuf[(pb * 4 + 0) * 17 + pjj]);
            float gf = sigm(gbuf[(pb * 4 + 1) * 17 + pjj]);
            float gg = sigm(gbuf[(pb * 4 + 2) * 17 + pjj]);  // sigmoid cell gate, per reference
            float go = sigm(gbuf[(pb * 4 + 3) * 17 + pjj]);
            cst = cst * gf + gi * gg;
            float h = go * tanhf(cst);
            __hip_bfloat16 hb = __float2bfloat16(h);
            unsigned short hbits;
            __builtin_memcpy(&hbits, &hb, 2);
            hpack[pb * 16 + pjj] = hbits;
        }
        __syncthreads();   // (4) hpack-sync

        // ---- wave 0 alone: packed coherent store of this WG's h slice + flag publish ----
        if (wave == 0) {
            const int sb   = lane >> 1;          // batch row 0..31
            const int half = lane & 1;           // which 8-col half
            const u64* hp = (const u64*)(hpack + sb * 16 + half * 8);
            u64 v0 = hp[0];
            u64 v1 = hp[1];
            u64* dst = (u64*)(hseq + ((size_t)t * B_ + sb) * H_ + w * 16 + half * 8);
            __hip_atomic_store(dst + 0, v0, __ATOMIC_RELAXED, __HIP_MEMORY_SCOPE_AGENT);
            __hip_atomic_store(dst + 1, v1, __ATOMIC_RELAXED, __HIP_MEMORY_SCOPE_AGENT);
            asm volatile("s_waitcnt vmcnt(0)" ::: "memory");   // h stores acked at coherence point
            if (lane == 0 && t < T_ - 1)
                __hip_atomic_store(flags + w * 16, (unsigned)(t + 1),
                                   __ATOMIC_RELAXED, __HIP_MEMORY_SCOPE_AGENT);
        }
        // other waves run ahead into step t+1's xg prefetch + poll barrier
    }
}

// ============ phase 4: expand hseq bf16 [T][B][H] -> out f32 [B][T][H] ============
__global__ __launch_bounds__(256) void expand_out(
    const __hip_bfloat16* __restrict__ hseq, float* __restrict__ out)
{
    const size_t gid = (size_t)blockIdx.x * 256 + threadIdx.x;   // 0 .. 2M-1
    const size_t lin = gid * 8;                    // element index in [T][B][H]
    const int t = (int)(lin >> 15);                // / (B_*H_)
    const int b = (int)((lin >> 10) & 31);
    const int h = (int)(lin & 1023);
    bf16x8 v = *(const bf16x8*)(hseq + lin);
    float* o = out + ((size_t)b * T_ + t) * H_ + h;
    #pragma unroll
    for (int i = 0; i < 8; ++i) {
        unsigned short s = (unsigned short)v[i];
        __hip_bfloat16 bv;
        __builtin_memcpy(&bv, &s, 2);
        o[i] = __bfloat162float(bv);
    }
}

// ============ fallback (round-1 slow path) if ws too small ============
__global__ __launch_bounds__(256) void lstm_step(
    const float* __restrict__ inp, const float* __restrict__ Wx,
    const float* __restrict__ bx, const float* __restrict__ Wh,
    const float* __restrict__ bh, float* __restrict__ out,
    float* __restrict__ c_state, int t)
{
    const int tid = threadIdx.x;
    const int lane = tid & 63;
    const int khalf = lane & 1;
    const int b = lane >> 1;
    const int j = blockIdx.x * 4 + (tid >> 6);
    const int k0 = khalf * (D_ / 2);
    float a0 = 0.f, a1 = 0.f, a2 = 0.f, a3 = 0.f;
    {
        const float* xrow = inp + ((size_t)b * T_ + t) * D_ + k0;
        const float* w0 = Wx + (size_t)(0 * H_ + j) * D_ + k0;
        const float* w1 = Wx + (size_t)(1 * H_ + j) * D_ + k0;
        const float* w2 = Wx + (size_t)(2 * H_ + j) * D_ + k0;
        const float* w3 = Wx + (size_t)(3 * H_ + j) * D_ + k0;
        for (int kk = 0; kk < D_ / 2; kk += 4) {
            float4 xv = *(const float4*)(xrow + kk);
            float4 v0 = *(const float4*)(w0 + kk), v1 = *(const float4*)(w1 + kk);
            float4 v2 = *(const float4*)(w2 + kk), v3 = *(const float4*)(w3 + kk);
            a0 = fmaf(xv.x, v0.x, fmaf(xv.y, v0.y, fmaf(xv.z, v0.z, fmaf(xv.w, v0.w, a0))));
            a1 = fmaf(xv.x, v1.x, fmaf(xv.y, v1.y, fmaf(xv.z, v1.z, fmaf(xv.w, v1.w, a1))));
            a2 = fmaf(xv.x, v2.x, fmaf(xv.y, v2.y, fmaf(xv.z, v2.z, fmaf(xv.w, v2.w, a2))));
            a3 = fmaf(xv.x, v3.x, fmaf(xv.y, v3.y, fmaf(xv.z, v3.z, fmaf(xv.w, v3.w, a3))));
        }
    }
    if (t > 0) {
        const float* hrow = out + ((size_t)b * T_ + (t - 1)) * H_ + k0;
        const float* w0 = Wh + (size_t)(0 * H_ + j) * H_ + k0;
        const float* w1 = Wh + (size_t)(1 * H_ + j) * H_ + k0;
        const float* w2 = Wh + (size_t)(2 * H_ + j) * H_ + k0;
        const float* w3 = Wh + (size_t)(3 * H_ + j) * H_ + k0;
        for (int kk = 0; kk < H_ / 2; kk += 4) {
            float4 hv = *(const float4*)(hrow + kk);
            float4 v0 = *(const float4*)(w0 + kk), v1 = *(const float4*)(w1 + kk);
            float4 v2 = *(const float4*)(w2 + kk), v3 = *(const float4*)(w3 + kk);
            a0 = fmaf(hv.x, v0.x, fmaf(hv.y, v0.y, fmaf(hv.z, v0.z, fmaf(hv.w, v0.w, a0))));
            a1 = fmaf(hv.x, v1.x, fmaf(hv.y, v1.y, fmaf(hv.z, v1.z, fmaf(hv.w, v1.w, a1))));
            a2 = fmaf(hv.x, v2.x, fmaf(hv.y, v2.y, fmaf(hv.z, v2.z, fmaf(hv.w, v2.w, a2))));
            a3 = fmaf(hv.x, v3.x, fmaf(hv.y, v3.y, fmaf(hv.z, v3.z, fmaf(hv.w, v3.w, a3))));
        }
    }
    a0 += __shfl_xor(a0, 1, 64); a1 += __shfl_xor(a1, 1, 64);
    a2 += __shfl_xor(a2, 1, 64); a3 += __shfl_xor(a3, 1, 64);
    if (khalf == 0) {
        float gi = sigm(a0 + bx[0 * H_ + j] + bh[0 * H_ + j]);
        float gf = sigm(a1 + bx[1 * H_ + j] + bh[1 * H_ + j]);
        float gg = sigm(a2 + bx[2 * H_ + j] + bh[2 * H_ + j]);
        float go = sigm(a3 + bx[3 * H_ + j] + bh[3 * H_ + j]);
        size_t ci = (size_t)b * H_ + j;
        float c = (t > 0) ? c_state[ci] : 0.0f;
        c = c * gf + gi * gg;
        c_state[ci] = c;
        out[((size_t)b * T_ + t) * H_ + j] = go * tanhf(c);
    }
}

extern "C" void kernel_launch(void* const* d_in, const int* in_sizes, int n_in,
                              void* d_out, int out_size, void* d_ws, size_t ws_size,
                              hipStream_t stream) {
    const float* inp = (const float*)d_in[0];
    const float* Wx  = (const float*)d_in[1];
    const float* bx  = (const float*)d_in[2];
    const float* Wh  = (const float*)d_in[3];
    const float* bh  = (const float*)d_in[4];
    float* out = (float*)d_out;
    char* ws = (char*)d_ws;

    if (ws_size < WS_NEEDED) {
        float* c_state = (float*)d_ws;
        for (int t = 0; t < T_; ++t)
            lstm_step<<<dim3(H_ / 4), dim3(256), 0, stream>>>(inp, Wx, bx, Wh, bh, out, c_state, t);
        return;
    }

    unsigned int*    flags = (unsigned int*)(ws + OFF_FLG);
    __hip_bfloat16*  Whb   = (__hip_bfloat16*)(ws + OFF_WHB);
    __hip_bfloat16*  Wxb   = (__hip_bfloat16*)(ws + OFF_WXB);
    __hip_bfloat16*  inp_b = (__hip_bfloat16*)(ws + OFF_INPB);  // becomes hseq after xg_gemm
    float*           bxh   = (float*)(ws + OFF_BXH);
    __hip_bfloat16*  xg    = (__hip_bfloat16*)(ws + OFF_XG);
    __hip_bfloat16*  hseq  = inp_b;

    hipMemsetAsync(flags, 0, 4096, stream);

    convert_all<<<dim3(4096), dim3(256), 0, stream>>>(inp, Wx, bx, Wh, bh, inp_b, Wxb, Whb, bxh);

    xg_gemm<<<dim3(BT / 128, G4 / 64), dim3(256), 0, stream>>>(inp_b, Wxb, bxh, xg);

    static bool attr_set = false;
    if (!attr_set) {
        hipFuncSetAttribute((const void*)lstm_scan,
                            hipFuncAttributeMaxDynamicSharedMemorySize, SMEM_TOTAL);
        attr_set = true;
    }
    lstm_scan<<<dim3(NWG), dim3(512), SMEM_TOTAL, stream>>>(xg, Whb, hseq, flags);

    expand_out<<<dim3((BT * H_ / 8) / 256), dim3(256), 0, stream>>>(hseq, out);
}

// Round 6
// 1943.602 us; speedup vs baseline: 2.3808x; 2.3808x over previous
//
#include <hip/hip_runtime.h>
#include <hip/hip_bf16.h>
#include <math.h>

#define B_ 32
#define T_ 512
#define D_ 1024
#define H_ 1024
#define G4 4096
#define BT 16384
#define NWG 64

using bf16x8 = __attribute__((ext_vector_type(8))) short;
using f32x4  = __attribute__((ext_vector_type(4))) float;
typedef unsigned long long u64;

__device__ __forceinline__ float sigm(float x) { return 1.0f / (1.0f + __expf(-x)); }

// ---- workspace layout (bytes) ----
#define OFF_FLG   0ull                         // 64 flags, 64B stride = 4096 B
#define OFF_HBUF  4096ull                      // (unused, layout stability)
#define OFF_WHB   (OFF_HBUF + 131072ull)       // Wh bf16 [4096][1024] = 8388608
#define OFF_WXB   (OFF_WHB + 8388608ull)       // Wx bf16 = 8388608
#define OFF_INPB  (OFF_WXB + 8388608ull)       // inp bf16 (reused as hseq[T][B][H]) = 33554432
#define OFF_BXH   (OFF_INPB + 33554432ull)     // bx+bh f32 [4096] = 16384
#define OFF_XG    (OFF_BXH + 16384ull)         // xg bf16 [T][NWG][4][32][16] = 134217728
#define WS_NEEDED (OFF_XG + 134217728ull)

// scan LDS: [0,65536) h-stage 32x2048B swizzled; [65536,74240) gbuf [32][4][17] f32;
// [74240,74244) lds_flag
#define SMEM_GBUF   65536
#define SMEM_LFLAG  74240
#define SMEM_TOTAL  74304

// ============ phase 1: convert inputs to bf16, fold biases ============
__global__ __launch_bounds__(256) void convert_all(
    const float* __restrict__ inp, const float* __restrict__ Wx,
    const float* __restrict__ bx, const float* __restrict__ Wh,
    const float* __restrict__ bh,
    __hip_bfloat16* __restrict__ inp_b, __hip_bfloat16* __restrict__ Wx_b,
    __hip_bfloat16* __restrict__ Wh_b, float* __restrict__ bxh)
{
    const int gid = blockIdx.x * 256 + threadIdx.x;   // 0 .. 1048575
    {
        const float4* s = (const float4*)inp + (size_t)gid * 4;
        #pragma unroll
        for (int v = 0; v < 4; ++v) {
            float4 f = s[v];
            size_t base = (size_t)gid * 16 + v * 4;
            inp_b[base + 0] = __float2bfloat16(f.x);
            inp_b[base + 1] = __float2bfloat16(f.y);
            inp_b[base + 2] = __float2bfloat16(f.z);
            inp_b[base + 3] = __float2bfloat16(f.w);
        }
    }
    {
        float4 fx = ((const float4*)Wx)[gid];
        float4 fh = ((const float4*)Wh)[gid];
        size_t base = (size_t)gid * 4;
        Wx_b[base + 0] = __float2bfloat16(fx.x);
        Wx_b[base + 1] = __float2bfloat16(fx.y);
        Wx_b[base + 2] = __float2bfloat16(fx.z);
        Wx_b[base + 3] = __float2bfloat16(fx.w);
        Wh_b[base + 0] = __float2bfloat16(fh.x);
        Wh_b[base + 1] = __float2bfloat16(fh.y);
        Wh_b[base + 2] = __float2bfloat16(fh.z);
        Wh_b[base + 3] = __float2bfloat16(fh.w);
    }
    if (gid < G4) bxh[gid] = bx[gid] + bh[gid];
}

// ============ phase 2: xg = X @ Wx^T + (bx+bh)  (m97-style 128x128 LDS-staged) ============
// grid (BT/128, G4/128), 256 threads (4 waves), BK=64, global_load_lds w16,
// T2 XOR-swizzle: linear LDS dest + pre-swizzled global source + swizzled ds_read.
__global__ __launch_bounds__(256) void xg_gemm(
    const __hip_bfloat16* __restrict__ X,    // [BT][D], row = b*T + t
    const __hip_bfloat16* __restrict__ Wxb,  // [G4][D]
    const float* __restrict__ bxh,           // [G4]
    __hip_bfloat16* __restrict__ xg)         // [T][NWG][4][32][16]
{
    __shared__ __align__(16) char As[16384];
    __shared__ __align__(16) char Bs[16384];

    const int m0 = blockIdx.x * 128;
    const int n0 = blockIdx.y * 128;
    const int tid = threadIdx.x;
    const int lane = tid & 63;
    const int wv = tid >> 6;              // 0..3
    const int vr = wv >> 1, vc = wv & 1;  // 64x64 quadrant
    const int l15 = lane & 15;
    const int kg = (lane >> 4) * 8;

    // staging geometry: wave wv, chunk c -> LDS rows wv*32+c*8+(lane>>3), colb (lane&7)*16
    const int srow_ = wv * 32 + (lane >> 3);
    const int scolb = (lane & 7) * 16;

    f32x4 acc[4][4] = {};

    for (int k0 = 0; k0 < D_; k0 += 64) {
        #pragma unroll
        for (int c = 0; c < 4; ++c) {
            const int row = srow_ + c * 8;
            const int cb  = scolb ^ ((row & 7) << 4);   // inverse-swizzled source col
            const char* ga = (const char*)X   + (size_t)(m0 + row) * 2048 + k0 * 2 + cb;
            const char* gb = (const char*)Wxb + (size_t)(n0 + row) * 2048 + k0 * 2 + cb;
            __builtin_amdgcn_global_load_lds(
                (const __attribute__((address_space(1))) void*)ga,
                (__attribute__((address_space(3))) void*)(As + wv * 4096 + c * 1024),
                16, 0, 0);
            __builtin_amdgcn_global_load_lds(
                (const __attribute__((address_space(1))) void*)gb,
                (__attribute__((address_space(3))) void*)(Bs + wv * 4096 + c * 1024),
                16, 0, 0);
        }
        __syncthreads();   // drains vmcnt -> tiles in LDS

        #pragma unroll
        for (int kk = 0; kk < 64; kk += 32) {
            bf16x8 af[4], bf[4];
            #pragma unroll
            for (int mi = 0; mi < 4; ++mi) {
                const int row = vr * 64 + mi * 16 + l15;
                af[mi] = *(const bf16x8*)(As + row * 128 + (((kk + kg) * 2) ^ ((row & 7) << 4)));
            }
            #pragma unroll
            for (int ni = 0; ni < 4; ++ni) {
                const int col = vc * 64 + ni * 16 + l15;
                bf[ni] = *(const bf16x8*)(Bs + col * 128 + (((kk + kg) * 2) ^ ((col & 7) << 4)));
            }
            #pragma unroll
            for (int mi = 0; mi < 4; ++mi)
                #pragma unroll
                for (int ni = 0; ni < 4; ++ni)
                    acc[mi][ni] = __builtin_amdgcn_mfma_f32_16x16x32_bf16(
                        af[mi], bf[ni], acc[mi][ni], 0, 0, 0);
        }
        __syncthreads();   // reads done before next stage
    }

    #pragma unroll
    for (int ni = 0; ni < 4; ++ni) {
        const int col = n0 + vc * 64 + ni * 16 + l15;
        const int qq = col >> 10, ww = (col >> 4) & 63, jj = col & 15;
        const float bias = bxh[col];
        #pragma unroll
        for (int mi = 0; mi < 4; ++mi) {
            const int r0 = m0 + vr * 64 + mi * 16 + ((lane >> 4) << 2);
            #pragma unroll
            for (int r = 0; r < 4; ++r) {
                const int row = r0 + r;                 // = b*T + t
                const int bb = row >> 9, tt = row & 511;
                xg[(((size_t)tt * NWG + ww) * 4 + qq) * 512 + bb * 16 + jj] =
                    __float2bfloat16(acc[mi][ni][r] + bias);
            }
        }
    }
}

// ============ phase 3: persistent recurrent scan ============
// 64 WGs x 512 threads. 3 barriers/step. wave0 polls 64 flags -> LDS-flag relay.
// h-stage via plain 16B loads (UC-written data, lines read exactly once, fresh via LLC).
// h published as in-wave shfl-packed u64 UC stores from all 8 waves in parallel.
__global__ __launch_bounds__(512, 2) void lstm_scan(
    const __hip_bfloat16* __restrict__ xg,    // [T][NWG][4][32][16] (bias folded)
    const __hip_bfloat16* __restrict__ Whb,   // [G4][H]
    __hip_bfloat16* __restrict__ hseq,        // [T][B][H]
    unsigned int* __restrict__ flags)         // [NWG] at 64B stride
{
    extern __shared__ char smem[];
    float* gbuf = (float*)(smem + SMEM_GBUF);
    int* lds_flag = (int*)(smem + SMEM_LFLAG);

    const int w    = blockIdx.x;
    const int tid  = threadIdx.x;
    const int lane = tid & 63;
    const int wave = tid >> 6;
    const int mwave = wave >> 2;
    const int q     = wave & 3;
    const int l15   = lane & 15;
    const int kg    = (lane >> 4) * 8;

    if (tid == 0) *lds_flag = 0;

    // ---- pin this wave's Wh B-fragments (UC loads; lands in AGPRs, MFMA reads natively) ----
    bf16x8 bfrag[32];
    {
        const char* wrow = (const char*)(Whb + (size_t)(q * 1024 + w * 16 + l15) * H_);
        #pragma unroll
        for (int i = 0; i < 32; ++i) {
            u64 lo = __hip_atomic_load((const u64*)(wrow + (i * 32 + kg) * 2),
                                       __ATOMIC_RELAXED, __HIP_MEMORY_SCOPE_AGENT);
            u64 hi = __hip_atomic_load((const u64*)(wrow + (i * 32 + kg) * 2 + 8),
                                       __ATOMIC_RELAXED, __HIP_MEMORY_SCOPE_AGENT);
            union { u64 qv[2]; bf16x8 v; } u;
            u.qv[0] = lo; u.qv[1] = hi;
            bfrag[i] = u.v;
        }
    }

    const int pb  = tid >> 4;          // batch 0..31
    const int pjj = tid & 15;
    float cst = 0.0f;

    const int dbr   = mwave * 16 + ((lane >> 4) << 2);
    const int arow  = mwave * 16 + l15;
    const int abase = arow * 2048;
    const int axor  = (arow & 7) << 4;
    const int srow  = wave * 4 + (lane >> 4);           // staging row 0..31
    const int ql    = lane & 15;

    for (int t = 0; t < T_; ++t) {
        // xg prefetch (independent of h; in flight during the wait)
        float xgv[4];
        {
            const size_t sbase = (((size_t)t * NWG + w) * 4 + q) * 512;
            #pragma unroll
            for (int r = 0; r < 4; ++r)
                xgv[r] = __bfloat162float(xg[sbase + (dbr + r) * 16 + l15]);
        }

        f32x4 acc = {};
        if (t > 0) {
            // ---- arrival: wave0 polls 64 flags, relays via LDS; others spin LDS ----
            if (wave == 0) {
                const unsigned int* fp = flags + lane * 16;
                while (__hip_atomic_load(fp, __ATOMIC_RELAXED, __HIP_MEMORY_SCOPE_AGENT)
                       < (unsigned)t)
                    __builtin_amdgcn_s_sleep(1);
                __hip_atomic_store(lds_flag, t, __ATOMIC_RELAXED,
                                   __HIP_MEMORY_SCOPE_WORKGROUP);
            } else {
                while (__hip_atomic_load(lds_flag, __ATOMIC_RELAXED,
                                         __HIP_MEMORY_SCOPE_WORKGROUP) < t)
                    __builtin_amdgcn_s_sleep(1);
            }
            asm volatile("" ::: "memory");

            // ---- stage h_{t-1} into LDS (plain 16B loads, XOR-swizzled writes) ----
            {
                const bf16x8* src = (const bf16x8*)(hseq + ((size_t)(t - 1) * B_ + srow) * H_);
                #pragma unroll
                for (int j = 0; j < 8; ++j) {
                    bf16x8 v = src[ql + j * 16];
                    *(bf16x8*)(smem + srow * 2048 + (((ql + j * 16) * 16) ^ ((srow & 7) << 4))) = v;
                }
            }
            __syncthreads();   // (A)

            // ---- 32 MFMAs, 4 accumulation chains ----
            f32x4 a0 = {}, a1 = {}, a2 = {}, a3 = {};
            #pragma unroll
            for (int i = 0; i < 8; ++i) {
                bf16x8 v0 = *(const bf16x8*)(smem + abase + ((((4 * i + 0) * 64) + kg * 2) ^ axor));
                bf16x8 v1 = *(const bf16x8*)(smem + abase + ((((4 * i + 1) * 64) + kg * 2) ^ axor));
                bf16x8 v2 = *(const bf16x8*)(smem + abase + ((((4 * i + 2) * 64) + kg * 2) ^ axor));
                bf16x8 v3 = *(const bf16x8*)(smem + abase + ((((4 * i + 3) * 64) + kg * 2) ^ axor));
                a0 = __builtin_amdgcn_mfma_f32_16x16x32_bf16(v0, bfrag[4 * i + 0], a0, 0, 0, 0);
                a1 = __builtin_amdgcn_mfma_f32_16x16x32_bf16(v1, bfrag[4 * i + 1], a1, 0, 0, 0);
                a2 = __builtin_amdgcn_mfma_f32_16x16x32_bf16(v2, bfrag[4 * i + 2], a2, 0, 0, 0);
                a3 = __builtin_amdgcn_mfma_f32_16x16x32_bf16(v3, bfrag[4 * i + 3], a3, 0, 0, 0);
            }
            acc = (a0 + a1) + (a2 + a3);
        }

        #pragma unroll
        for (int r = 0; r < 4; ++r)
            gbuf[((dbr + r) * 4 + q) * 17 + l15] = acc[r] + xgv[r];
        __syncthreads();   // (B)

        // ---- pointwise; pack h in-wave; parallel UC stores ----
        {
            float gi = sigm(gbuf[(pb * 4 + 0) * 17 + pjj]);
            float gf = sigm(gbuf[(pb * 4 + 1) * 17 + pjj]);
            float gg = sigm(gbuf[(pb * 4 + 2) * 17 + pjj]);  // sigmoid cell gate, per reference
            float go = sigm(gbuf[(pb * 4 + 3) * 17 + pjj]);
            cst = cst * gf + gi * gg;
            float h = go * tanhf(cst);
            __hip_bfloat16 hb = __float2bfloat16(h);
            unsigned short hs_;
            __builtin_memcpy(&hs_, &hb, 2);
            unsigned hu = hs_;
            unsigned h1 = __shfl_down(hu, 1, 64);
            unsigned h2 = __shfl_down(hu, 2, 64);
            unsigned h3 = __shfl_down(hu, 3, 64);
            if ((lane & 3) == 0) {
                u64 pv = (u64)hu | ((u64)h1 << 16) | ((u64)h2 << 32) | ((u64)h3 << 48);
                u64* dst = (u64*)(hseq + ((size_t)t * B_ + pb) * H_ + w * 16 + pjj);
                __hip_atomic_store(dst, pv, __ATOMIC_RELAXED, __HIP_MEMORY_SCOPE_AGENT);
            }
        }
        __syncthreads();   // (C) drains vmcnt -> all h stores acked at coherence point

        if (t < T_ - 1 && tid == 0)
            __hip_atomic_store(flags + w * 16, (unsigned)(t + 1),
                               __ATOMIC_RELAXED, __HIP_MEMORY_SCOPE_AGENT);
    }
}

// ============ phase 4: expand hseq bf16 [T][B][H] -> out f32 [B][T][H] ============
__global__ __launch_bounds__(256) void expand_out(
    const __hip_bfloat16* __restrict__ hseq, float* __restrict__ out)
{
    const size_t gid = (size_t)blockIdx.x * 256 + threadIdx.x;
    const size_t lin = gid * 8;
    const int t = (int)(lin >> 15);
    const int b = (int)((lin >> 10) & 31);
    const int h = (int)(lin & 1023);
    bf16x8 v = *(const bf16x8*)(hseq + lin);
    float* o = out + ((size_t)b * T_ + t) * H_ + h;
    #pragma unroll
    for (int i = 0; i < 8; ++i) {
        unsigned short s = (unsigned short)v[i];
        __hip_bfloat16 bv;
        __builtin_memcpy(&bv, &s, 2);
        o[i] = __bfloat162float(bv);
    }
}

// ============ fallback (round-1 slow path) if ws too small ============
__global__ __launch_bounds__(256) void lstm_step(
    const float* __restrict__ inp, const float* __restrict__ Wx,
    const float* __restrict__ bx, const float* __restrict__ Wh,
    const float* __restrict__ bh, float* __restrict__ out,
    float* __restrict__ c_state, int t)
{
    const int tid = threadIdx.x;
    const int lane = tid & 63;
    const int khalf = lane & 1;
    const int b = lane >> 1;
    const int j = blockIdx.x * 4 + (tid >> 6);
    const int k0 = khalf * (D_ / 2);
    float a0 = 0.f, a1 = 0.f, a2 = 0.f, a3 = 0.f;
    {
        const float* xrow = inp + ((size_t)b * T_ + t) * D_ + k0;
        const float* w0 = Wx + (size_t)(0 * H_ + j) * D_ + k0;
        const float* w1 = Wx + (size_t)(1 * H_ + j) * D_ + k0;
        const float* w2 = Wx + (size_t)(2 * H_ + j) * D_ + k0;
        const float* w3 = Wx + (size_t)(3 * H_ + j) * D_ + k0;
        for (int kk = 0; kk < D_ / 2; kk += 4) {
            float4 xv = *(const float4*)(xrow + kk);
            float4 v0 = *(const float4*)(w0 + kk), v1 = *(const float4*)(w1 + kk);
            float4 v2 = *(const float4*)(w2 + kk), v3 = *(const float4*)(w3 + kk);
            a0 = fmaf(xv.x, v0.x, fmaf(xv.y, v0.y, fmaf(xv.z, v0.z, fmaf(xv.w, v0.w, a0))));
            a1 = fmaf(xv.x, v1.x, fmaf(xv.y, v1.y, fmaf(xv.z, v1.z, fmaf(xv.w, v1.w, a1))));
            a2 = fmaf(xv.x, v2.x, fmaf(xv.y, v2.y, fmaf(xv.z, v2.z, fmaf(xv.w, v2.w, a2))));
            a3 = fmaf(xv.x, v3.x, fmaf(xv.y, v3.y, fmaf(xv.z, v3.z, fmaf(xv.w, v3.w, a3))));
        }
    }
    if (t > 0) {
        const float* hrow = out + ((size_t)b * T_ + (t - 1)) * H_ + k0;
        const float* w0 = Wh + (size_t)(0 * H_ + j) * H_ + k0;
        const float* w1 = Wh + (size_t)(1 * H_ + j) * H_ + k0;
        const float* w2 = Wh + (size_t)(2 * H_ + j) * H_ + k0;
        const float* w3 = Wh + (size_t)(3 * H_ + j) * H_ + k0;
        for (int kk = 0; kk < H_ / 2; kk += 4) {
            float4 hv = *(const float4*)(hrow + kk);
            float4 v0 = *(const float4*)(w0 + kk), v1 = *(const float4*)(w1 + kk);
            float4 v2 = *(const float4*)(w2 + kk), v3 = *(const float4*)(w3 + kk);
            a0 = fmaf(hv.x, v0.x, fmaf(hv.y, v0.y, fmaf(hv.z, v0.z, fmaf(hv.w, v0.w, a0))));
            a1 = fmaf(hv.x, v1.x, fmaf(hv.y, v1.y, fmaf(hv.z, v1.z, fmaf(hv.w, v1.w, a1))));
            a2 = fmaf(hv.x, v2.x, fmaf(hv.y, v2.y, fmaf(hv.z, v2.z, fmaf(hv.w, v2.w, a2))));
            a3 = fmaf(hv.x, v3.x, fmaf(hv.y, v3.y, fmaf(hv.z, v3.z, fmaf(hv.w, v3.w, a3))));
        }
    }
    a0 += __shfl_xor(a0, 1, 64); a1 += __shfl_xor(a1, 1, 64);
    a2 += __shfl_xor(a2, 1, 64); a3 += __shfl_xor(a3, 1, 64);
    if (khalf == 0) {
        float gi = sigm(a0 + bx[0 * H_ + j] + bh[0 * H_ + j]);
        float gf = sigm(a1 + bx[1 * H_ + j] + bh[1 * H_ + j]);
        float gg = sigm(a2 + bx[2 * H_ + j] + bh[2 * H_ + j]);
        float go = sigm(a3 + bx[3 * H_ + j] + bh[3 * H_ + j]);
        size_t ci = (size_t)b * H_ + j;
        float c = (t > 0) ? c_state[ci] : 0.0f;
        c = c * gf + gi * gg;
        c_state[ci] = c;
        out[((size_t)b * T_ + t) * H_ + j] = go * tanhf(c);
    }
}

extern "C" void kernel_launch(void* const* d_in, const int* in_sizes, int n_in,
                              void* d_out, int out_size, void* d_ws, size_t ws_size,
                              hipStream_t stream) {
    const float* inp = (const float*)d_in[0];
    const float* Wx  = (const float*)d_in[1];
    const float* bx  = (const float*)d_in[2];
    const float* Wh  = (const float*)d_in[3];
    const float* bh  = (const float*)d_in[4];
    float* out = (float*)d_out;
    char* ws = (char*)d_ws;

    if (ws_size < WS_NEEDED) {
        float* c_state = (float*)d_ws;
        for (int t = 0; t < T_; ++t)
            lstm_step<<<dim3(H_ / 4), dim3(256), 0, stream>>>(inp, Wx, bx, Wh, bh, out, c_state, t);
        return;
    }

    unsigned int*    flags = (unsigned int*)(ws + OFF_FLG);
    __hip_bfloat16*  Whb   = (__hip_bfloat16*)(ws + OFF_WHB);
    __hip_bfloat16*  Wxb   = (__hip_bfloat16*)(ws + OFF_WXB);
    __hip_bfloat16*  inp_b = (__hip_bfloat16*)(ws + OFF_INPB);  // becomes hseq after xg_gemm
    float*           bxh   = (float*)(ws + OFF_BXH);
    __hip_bfloat16*  xg    = (__hip_bfloat16*)(ws + OFF_XG);
    __hip_bfloat16*  hseq  = inp_b;

    hipMemsetAsync(flags, 0, 4096, stream);

    convert_all<<<dim3(4096), dim3(256), 0, stream>>>(inp, Wx, bx, Wh, bh, inp_b, Wxb, Whb, bxh);

    xg_gemm<<<dim3(BT / 128, G4 / 128), dim3(256), 0, stream>>>(inp_b, Wxb, bxh, xg);

    static bool attr_set = false;
    if (!attr_set) {
        hipFuncSetAttribute((const void*)lstm_scan,
                            hipFuncAttributeMaxDynamicSharedMemorySize, SMEM_TOTAL);
        attr_set = true;
    }
    lstm_scan<<<dim3(NWG), dim3(512), SMEM_TOTAL, stream>>>(xg, Whb, hseq, flags);

    expand_out<<<dim3((BT * H_ / 8) / 256), dim3(256), 0, stream>>>(hseq, out);
}

// Round 7
// 1942.500 us; speedup vs baseline: 2.3822x; 1.0006x over previous
//
#include <hip/hip_runtime.h>
#include <hip/hip_bf16.h>
#include <math.h>

#define B_ 32
#define T_ 512
#define D_ 1024
#define H_ 1024
#define G4 4096
#define BT 16384
#define NWG 64

using bf16x8 = __attribute__((ext_vector_type(8))) short;
using f32x4  = __attribute__((ext_vector_type(4))) float;
typedef unsigned long long u64;

__device__ __forceinline__ float sigm(float x) { return 1.0f / (1.0f + __expf(-x)); }

// ---- workspace layout (bytes) ----
#define OFF_FLG   0ull                         // 64 flags, 64B stride = 4096 B
#define OFF_HBUF  4096ull                      // (unused, layout stability)
#define OFF_WHB   (OFF_HBUF + 131072ull)       // Wh bf16 [4096][1024] = 8388608
#define OFF_WXB   (OFF_WHB + 8388608ull)       // Wx bf16 = 8388608
#define OFF_INPB  (OFF_WXB + 8388608ull)       // inp bf16 (reused as hseq[T][B][H]) = 33554432
#define OFF_BXH   (OFF_INPB + 33554432ull)     // bx+bh f32 [4096] = 16384
#define OFF_XG    (OFF_BXH + 16384ull)         // xg bf16 [T][NWG][4][32][16] = 134217728
#define WS_NEEDED (OFF_XG + 134217728ull)

// scan LDS: [0,65536) h-stage 32x2048B swizzled; [65536,74240) gbuf [32][4][17] f32;
// [74240,74244) lds_flag
#define SMEM_GBUF   65536
#define SMEM_LFLAG  74240
#define SMEM_TOTAL  74304

// ============ phase 1: convert inputs to bf16, fold biases ============
__global__ __launch_bounds__(256) void convert_all(
    const float* __restrict__ inp, const float* __restrict__ Wx,
    const float* __restrict__ bx, const float* __restrict__ Wh,
    const float* __restrict__ bh,
    __hip_bfloat16* __restrict__ inp_b, __hip_bfloat16* __restrict__ Wx_b,
    __hip_bfloat16* __restrict__ Wh_b, float* __restrict__ bxh)
{
    const int gid = blockIdx.x * 256 + threadIdx.x;   // 0 .. 1048575
    {
        const float4* s = (const float4*)inp + (size_t)gid * 4;
        #pragma unroll
        for (int v = 0; v < 4; ++v) {
            float4 f = s[v];
            size_t base = (size_t)gid * 16 + v * 4;
            inp_b[base + 0] = __float2bfloat16(f.x);
            inp_b[base + 1] = __float2bfloat16(f.y);
            inp_b[base + 2] = __float2bfloat16(f.z);
            inp_b[base + 3] = __float2bfloat16(f.w);
        }
    }
    {
        float4 fx = ((const float4*)Wx)[gid];
        float4 fh = ((const float4*)Wh)[gid];
        size_t base = (size_t)gid * 4;
        Wx_b[base + 0] = __float2bfloat16(fx.x);
        Wx_b[base + 1] = __float2bfloat16(fx.y);
        Wx_b[base + 2] = __float2bfloat16(fx.z);
        Wx_b[base + 3] = __float2bfloat16(fx.w);
        Wh_b[base + 0] = __float2bfloat16(fh.x);
        Wh_b[base + 1] = __float2bfloat16(fh.y);
        Wh_b[base + 2] = __float2bfloat16(fh.z);
        Wh_b[base + 3] = __float2bfloat16(fh.w);
    }
    if (gid < G4) bxh[gid] = bx[gid] + bh[gid];
}

// ============ phase 2: xg = X @ Wx^T + (bx+bh)  (m97-style 128x128 LDS-staged) ============
// grid (BT/128, G4/128), 256 threads (4 waves), BK=64, global_load_lds w16,
// T2 XOR-swizzle: linear LDS dest + pre-swizzled global source + swizzled ds_read.
__global__ __launch_bounds__(256) void xg_gemm(
    const __hip_bfloat16* __restrict__ X,    // [BT][D], row = b*T + t
    const __hip_bfloat16* __restrict__ Wxb,  // [G4][D]
    const float* __restrict__ bxh,           // [G4]
    __hip_bfloat16* __restrict__ xg)         // [T][NWG][4][32][16]
{
    __shared__ __align__(16) char As[16384];
    __shared__ __align__(16) char Bs[16384];

    const int m0 = blockIdx.x * 128;
    const int n0 = blockIdx.y * 128;
    const int tid = threadIdx.x;
    const int lane = tid & 63;
    const int wv = tid >> 6;              // 0..3
    const int vr = wv >> 1, vc = wv & 1;  // 64x64 quadrant
    const int l15 = lane & 15;
    const int kg = (lane >> 4) * 8;

    // staging geometry: wave wv, chunk c -> LDS rows wv*32+c*8+(lane>>3), colb (lane&7)*16
    const int srow_ = wv * 32 + (lane >> 3);
    const int scolb = (lane & 7) * 16;

    f32x4 acc[4][4] = {};

    for (int k0 = 0; k0 < D_; k0 += 64) {
        #pragma unroll
        for (int c = 0; c < 4; ++c) {
            const int row = srow_ + c * 8;
            const int cb  = scolb ^ ((row & 7) << 4);   // inverse-swizzled source col
            const char* ga = (const char*)X   + (size_t)(m0 + row) * 2048 + k0 * 2 + cb;
            const char* gb = (const char*)Wxb + (size_t)(n0 + row) * 2048 + k0 * 2 + cb;
            __builtin_amdgcn_global_load_lds(
                (const __attribute__((address_space(1))) void*)ga,
                (__attribute__((address_space(3))) void*)(As + wv * 4096 + c * 1024),
                16, 0, 0);
            __builtin_amdgcn_global_load_lds(
                (const __attribute__((address_space(1))) void*)gb,
                (__attribute__((address_space(3))) void*)(Bs + wv * 4096 + c * 1024),
                16, 0, 0);
        }
        __syncthreads();   // drains vmcnt -> tiles in LDS

        #pragma unroll
        for (int kk = 0; kk < 64; kk += 32) {
            bf16x8 af[4], bf[4];
            #pragma unroll
            for (int mi = 0; mi < 4; ++mi) {
                const int row = vr * 64 + mi * 16 + l15;
                af[mi] = *(const bf16x8*)(As + row * 128 + (((kk + kg) * 2) ^ ((row & 7) << 4)));
            }
            #pragma unroll
            for (int ni = 0; ni < 4; ++ni) {
                const int col = vc * 64 + ni * 16 + l15;
                bf[ni] = *(const bf16x8*)(Bs + col * 128 + (((kk + kg) * 2) ^ ((col & 7) << 4)));
            }
            #pragma unroll
            for (int mi = 0; mi < 4; ++mi)
                #pragma unroll
                for (int ni = 0; ni < 4; ++ni)
                    acc[mi][ni] = __builtin_amdgcn_mfma_f32_16x16x32_bf16(
                        af[mi], bf[ni], acc[mi][ni], 0, 0, 0);
        }
        __syncthreads();   // reads done before next stage
    }

    #pragma unroll
    for (int ni = 0; ni < 4; ++ni) {
        const int col = n0 + vc * 64 + ni * 16 + l15;
        const int qq = col >> 10, ww = (col >> 4) & 63, jj = col & 15;
        const float bias = bxh[col];
        #pragma unroll
        for (int mi = 0; mi < 4; ++mi) {
            const int r0 = m0 + vr * 64 + mi * 16 + ((lane >> 4) << 2);
            #pragma unroll
            for (int r = 0; r < 4; ++r) {
                const int row = r0 + r;                 // = b*T + t
                const int bb = row >> 9, tt = row & 511;
                xg[(((size_t)tt * NWG + ww) * 4 + qq) * 512 + bb * 16 + jj] =
                    __float2bfloat16(acc[mi][ni][r] + bias);
            }
        }
    }
}

// ============ phase 3: persistent recurrent scan ============
// 64 WGs x 512 threads. 3 barriers/step. wave0 polls 64 flags -> LDS-flag relay.
// h-stage via plain 16B loads (UC-written data, lines read exactly once, fresh via LLC).
// h published as in-wave shfl-packed u64 UC stores from all 8 waves in parallel.
__global__ __launch_bounds__(512, 2) void lstm_scan(
    const __hip_bfloat16* __restrict__ xg,    // [T][NWG][4][32][16] (bias folded)
    const __hip_bfloat16* __restrict__ Whb,   // [G4][H]
    __hip_bfloat16* __restrict__ hseq,        // [T][B][H]
    unsigned int* __restrict__ flags)         // [NWG] at 64B stride
{
    extern __shared__ char smem[];
    float* gbuf = (float*)(smem + SMEM_GBUF);
    int* lds_flag = (int*)(smem + SMEM_LFLAG);

    const int w    = blockIdx.x;
    const int tid  = threadIdx.x;
    const int lane = tid & 63;
    const int wave = tid >> 6;
    const int mwave = wave >> 2;
    const int q     = wave & 3;
    const int l15   = lane & 15;
    const int kg    = (lane >> 4) * 8;

    if (tid == 0) *lds_flag = 0;

    // ---- pin this wave's Wh B-fragments (UC loads; lands in AGPRs, MFMA reads natively) ----
    bf16x8 bfrag[32];
    {
        const char* wrow = (const char*)(Whb + (size_t)(q * 1024 + w * 16 + l15) * H_);
        #pragma unroll
        for (int i = 0; i < 32; ++i) {
            u64 lo = __hip_atomic_load((const u64*)(wrow + (i * 32 + kg) * 2),
                                       __ATOMIC_RELAXED, __HIP_MEMORY_SCOPE_AGENT);
            u64 hi = __hip_atomic_load((const u64*)(wrow + (i * 32 + kg) * 2 + 8),
                                       __ATOMIC_RELAXED, __HIP_MEMORY_SCOPE_AGENT);
            union { u64 qv[2]; bf16x8 v; } u;
            u.qv[0] = lo; u.qv[1] = hi;
            bfrag[i] = u.v;
        }
    }

    const int pb  = tid >> 4;          // batch 0..31
    const int pjj = tid & 15;
    float cst = 0.0f;

    const int dbr   = mwave * 16 + ((lane >> 4) << 2);
    const int arow  = mwave * 16 + l15;
    const int abase = arow * 2048;
    const int axor  = (arow & 7) << 4;
    const int srow  = wave * 4 + (lane >> 4);           // staging row 0..31
    const int ql    = lane & 15;

    for (int t = 0; t < T_; ++t) {
        // xg prefetch (independent of h; in flight during the wait)
        float xgv[4];
        {
            const size_t sbase = (((size_t)t * NWG + w) * 4 + q) * 512;
            #pragma unroll
            for (int r = 0; r < 4; ++r)
                xgv[r] = __bfloat162float(xg[sbase + (dbr + r) * 16 + l15]);
        }

        f32x4 acc = {};
        if (t > 0) {
            // ---- arrival: wave0 polls 64 flags, relays via LDS; others spin LDS ----
            if (wave == 0) {
                const unsigned int* fp = flags + lane * 16;
                while (__hip_atomic_load(fp, __ATOMIC_RELAXED, __HIP_MEMORY_SCOPE_AGENT)
                       < (unsigned)t)
                    __builtin_amdgcn_s_sleep(1);
                __hip_atomic_store(lds_flag, t, __ATOMIC_RELAXED,
                                   __HIP_MEMORY_SCOPE_WORKGROUP);
            } else {
                while (__hip_atomic_load(lds_flag, __ATOMIC_RELAXED,
                                         __HIP_MEMORY_SCOPE_WORKGROUP) < t)
                    __builtin_amdgcn_s_sleep(1);
            }
            asm volatile("" ::: "memory");

            // ---- stage h_{t-1} into LDS (plain 16B loads, XOR-swizzled writes) ----
            {
                const bf16x8* src = (const bf16x8*)(hseq + ((size_t)(t - 1) * B_ + srow) * H_);
                #pragma unroll
                for (int j = 0; j < 8; ++j) {
                    bf16x8 v = src[ql + j * 16];
                    *(bf16x8*)(smem + srow * 2048 + (((ql + j * 16) * 16) ^ ((srow & 7) << 4))) = v;
                }
            }
            __syncthreads();   // (A)

            // ---- 32 MFMAs, 4 accumulation chains ----
            f32x4 a0 = {}, a1 = {}, a2 = {}, a3 = {};
            #pragma unroll
            for (int i = 0; i < 8; ++i) {
                bf16x8 v0 = *(const bf16x8*)(smem + abase + ((((4 * i + 0) * 64) + kg * 2) ^ axor));
                bf16x8 v1 = *(const bf16x8*)(smem + abase + ((((4 * i + 1) * 64) + kg * 2) ^ axor));
                bf16x8 v2 = *(const bf16x8*)(smem + abase + ((((4 * i + 2) * 64) + kg * 2) ^ axor));
                bf16x8 v3 = *(const bf16x8*)(smem + abase + ((((4 * i + 3) * 64) + kg * 2) ^ axor));
                a0 = __builtin_amdgcn_mfma_f32_16x16x32_bf16(v0, bfrag[4 * i + 0], a0, 0, 0, 0);
                a1 = __builtin_amdgcn_mfma_f32_16x16x32_bf16(v1, bfrag[4 * i + 1], a1, 0, 0, 0);
                a2 = __builtin_amdgcn_mfma_f32_16x16x32_bf16(v2, bfrag[4 * i + 2], a2, 0, 0, 0);
                a3 = __builtin_amdgcn_mfma_f32_16x16x32_bf16(v3, bfrag[4 * i + 3], a3, 0, 0, 0);
            }
            acc = (a0 + a1) + (a2 + a3);
        }

        #pragma unroll
        for (int r = 0; r < 4; ++r)
            gbuf[((dbr + r) * 4 + q) * 17 + l15] = acc[r] + xgv[r];
        __syncthreads();   // (B)

        // ---- pointwise; pack h in-wave; parallel UC stores ----
        {
            float gi = sigm(gbuf[(pb * 4 + 0) * 17 + pjj]);
            float gf = sigm(gbuf[(pb * 4 + 1) * 17 + pjj]);
            float gg = sigm(gbuf[(pb * 4 + 2) * 17 + pjj]);  // sigmoid cell gate, per reference
            float go = sigm(gbuf[(pb * 4 + 3) * 17 + pjj]);
            cst = cst * gf + gi * gg;
            float h = go * tanhf(cst);
            __hip_bfloat16 hb = __float2bfloat16(h);
            unsigned short hs_;
            __builtin_memcpy(&hs_, &hb, 2);
            unsigned hu = hs_;
            unsigned h1 = __shfl_down(hu, 1, 64);
            unsigned h2 = __shfl_down(hu, 2, 64);
            unsigned h3 = __shfl_down(hu, 3, 64);
            if ((lane & 3) == 0) {
                u64 pv = (u64)hu | ((u64)h1 << 16) | ((u64)h2 << 32) | ((u64)h3 << 48);
                u64* dst = (u64*)(hseq + ((size_t)t * B_ + pb) * H_ + w * 16 + pjj);
                __hip_atomic_store(dst, pv, __ATOMIC_RELAXED, __HIP_MEMORY_SCOPE_AGENT);
            }
        }
        __syncthreads();   // (C) drains vmcnt -> all h stores acked at coherence point

        if (t < T_ - 1 && tid == 0)
            __hip_atomic_store(flags + w * 16, (unsigned)(t + 1),
                               __ATOMIC_RELAXED, __HIP_MEMORY_SCOPE_AGENT);
    }
}

// ============ phase 4: expand hseq bf16 [T][B][H] -> out f32 [B][T][H] ============
__global__ __launch_bounds__(256) void expand_out(
    const __hip_bfloat16* __restrict__ hseq, float* __restrict__ out)
{
    const size_t gid = (size_t)blockIdx.x * 256 + threadIdx.x;
    const size_t lin = gid * 8;
    const int t = (int)(lin >> 15);
    const int b = (int)((lin >> 10) & 31);
    const int h = (int)(lin & 1023);
    bf16x8 v = *(const bf16x8*)(hseq + lin);
    float* o = out + ((size_t)b * T_ + t) * H_ + h;
    #pragma unroll
    for (int i = 0; i < 8; ++i) {
        unsigned short s = (unsigned short)v[i];
        __hip_bfloat16 bv;
        __builtin_memcpy(&bv, &s, 2);
        o[i] = __bfloat162float(bv);
    }
}

// ============ fallback (round-1 slow path) if ws too small ============
__global__ __launch_bounds__(256) void lstm_step(
    const float* __restrict__ inp, const float* __restrict__ Wx,
    const float* __restrict__ bx, const float* __restrict__ Wh,
    const float* __restrict__ bh, float* __restrict__ out,
    float* __restrict__ c_state, int t)
{
    const int tid = threadIdx.x;
    const int lane = tid & 63;
    const int khalf = lane & 1;
    const int b = lane >> 1;
    const int j = blockIdx.x * 4 + (tid >> 6);
    const int k0 = khalf * (D_ / 2);
    float a0 = 0.f, a1 = 0.f, a2 = 0.f, a3 = 0.f;
    {
        const float* xrow = inp + ((size_t)b * T_ + t) * D_ + k0;
        const float* w0 = Wx + (size_t)(0 * H_ + j) * D_ + k0;
        const float* w1 = Wx + (size_t)(1 * H_ + j) * D_ + k0;
        const float* w2 = Wx + (size_t)(2 * H_ + j) * D_ + k0;
        const float* w3 = Wx + (size_t)(3 * H_ + j) * D_ + k0;
        for (int kk = 0; kk < D_ / 2; kk += 4) {
            float4 xv = *(const float4*)(xrow + kk);
            float4 v0 = *(const float4*)(w0 + kk), v1 = *(const float4*)(w1 + kk);
            float4 v2 = *(const float4*)(w2 + kk), v3 = *(const float4*)(w3 + kk);
            a0 = fmaf(xv.x, v0.x, fmaf(xv.y, v0.y, fmaf(xv.z, v0.z, fmaf(xv.w, v0.w, a0))));
            a1 = fmaf(xv.x, v1.x, fmaf(xv.y, v1.y, fmaf(xv.z, v1.z, fmaf(xv.w, v1.w, a1))));
            a2 = fmaf(xv.x, v2.x, fmaf(xv.y, v2.y, fmaf(xv.z, v2.z, fmaf(xv.w, v2.w, a2))));
            a3 = fmaf(xv.x, v3.x, fmaf(xv.y, v3.y, fmaf(xv.z, v3.z, fmaf(xv.w, v3.w, a3))));
        }
    }
    if (t > 0) {
        const float* hrow = out + ((size_t)b * T_ + (t - 1)) * H_ + k0;
        const float* w0 = Wh + (size_t)(0 * H_ + j) * H_ + k0;
        const float* w1 = Wh + (size_t)(1 * H_ + j) * H_ + k0;
        const float* w2 = Wh + (size_t)(2 * H_ + j) * H_ + k0;
        const float* w3 = Wh + (size_t)(3 * H_ + j) * H_ + k0;
        for (int kk = 0; kk < H_ / 2; kk += 4) {
            float4 hv = *(const float4*)(hrow + kk);
            float4 v0 = *(const float4*)(w0 + kk), v1 = *(const float4*)(w1 + kk);
            float4 v2 = *(const float4*)(w2 + kk), v3 = *(const float4*)(w3 + kk);
            a0 = fmaf(hv.x, v0.x, fmaf(hv.y, v0.y, fmaf(hv.z, v0.z, fmaf(hv.w, v0.w, a0))));
            a1 = fmaf(hv.x, v1.x, fmaf(hv.y, v1.y, fmaf(hv.z, v1.z, fmaf(hv.w, v1.w, a1))));
            a2 = fmaf(hv.x, v2.x, fmaf(hv.y, v2.y, fmaf(hv.z, v2.z, fmaf(hv.w, v2.w, a2))));
            a3 = fmaf(hv.x, v3.x, fmaf(hv.y, v3.y, fmaf(hv.z, v3.z, fmaf(hv.w, v3.w, a3))));
        }
    }
    a0 += __shfl_xor(a0, 1, 64); a1 += __shfl_xor(a1, 1, 64);
    a2 += __shfl_xor(a2, 1, 64); a3 += __shfl_xor(a3, 1, 64);
    if (khalf == 0) {
        float gi = sigm(a0 + bx[0 * H_ + j] + bh[0 * H_ + j]);
        float gf = sigm(a1 + bx[1 * H_ + j] + bh[1 * H_ + j]);
        float gg = sigm(a2 + bx[2 * H_ + j] + bh[2 * H_ + j]);
        float go = sigm(a3 + bx[3 * H_ + j] + bh[3 * H_ + j]);
        size_t ci = (size_t)b * H_ + j;
        float c = (t > 0) ? c_state[ci] : 0.0f;
        c = c * gf + gi * gg;
        c_state[ci] = c;
        out[((size_t)b * T_ + t) * H_ + j] = go * tanhf(c);
    }
}

extern "C" void kernel_launch(void* const* d_in, const int* in_sizes, int n_in,
                              void* d_out, int out_size, void* d_ws, size_t ws_size,
                              hipStream_t stream) {
    const float* inp = (const float*)d_in[0];
    const float* Wx  = (const float*)d_in[1];
    const float* bx  = (const float*)d_in[2];
    const float* Wh  = (const float*)d_in[3];
    const float* bh  = (const float*)d_in[4];
    float* out = (float*)d_out;
    char* ws = (char*)d_ws;

    if (ws_size < WS_NEEDED) {
        float* c_state = (float*)d_ws;
        for (int t = 0; t < T_; ++t)
            lstm_step<<<dim3(H_ / 4), dim3(256), 0, stream>>>(inp, Wx, bx, Wh, bh, out, c_state, t);
        return;
    }

    unsigned int*    flags = (unsigned int*)(ws + OFF_FLG);
    __hip_bfloat16*  Whb   = (__hip_bfloat16*)(ws + OFF_WHB);
    __hip_bfloat16*  Wxb   = (__hip_bfloat16*)(ws + OFF_WXB);
    __hip_bfloat16*  inp_b = (__hip_bfloat16*)(ws + OFF_INPB);  // becomes hseq after xg_gemm
    float*           bxh   = (float*)(ws + OFF_BXH);
    __hip_bfloat16*  xg    = (__hip_bfloat16*)(ws + OFF_XG);
    __hip_bfloat16*  hseq  = inp_b;

    hipMemsetAsync(flags, 0, 4096, stream);

    convert_all<<<dim3(4096), dim3(256), 0, stream>>>(inp, Wx, bx, Wh, bh, inp_b, Wxb, Whb, bxh);

    xg_gemm<<<dim3(BT / 128, G4 / 128), dim3(256), 0, stream>>>(inp_b, Wxb, bxh, xg);

    static bool attr_set = false;
    if (!attr_set) {
        hipFuncSetAttribute((const void*)lstm_scan,
                            hipFuncAttributeMaxDynamicSharedMemorySize, SMEM_TOTAL);
        attr_set = true;
    }
    lstm_scan<<<dim3(NWG), dim3(512), SMEM_TOTAL, stream>>>(xg, Whb, hseq, flags);

    expand_out<<<dim3((BT * H_ / 8) / 256), dim3(256), 0, stream>>>(hseq, out);
}